// Round 3
// baseline (308.610 us; speedup 1.0000x reference)
//
#include <hip/hip_runtime.h>
#include <hip/hip_cooperative_groups.h>
#include <math.h>

namespace cg = cooperative_groups;

// Problem constants (fixed by reference setup_inputs)
constexpr int B = 64;
constexpr int S = 1024;
constexpr int D = 256;
constexpr int NNEG = 32;
constexpr int CH = 16;                  // chunks per chain
constexpr int ROWS = S / CH;            // 64 rows per chunk/block
constexpr int GRID = B * CH;            // 1024 blocks = 4 per CU
constexpr int NPAIR = B * (B - 1) / 2;  // 2016
constexpr int NCELL = B * B;            // 4096 gram cells
#define EPSN 1e-8f

__device__ __forceinline__ float block_sum256(float v, volatile float* red,
                                              int wave, int lane) {
    #pragma unroll
    for (int m = 1; m < 64; m <<= 1) v += __shfl_xor(v, m, 64);
    if (lane == 0) red[wave] = v;
    __syncthreads();
    v = red[0] + red[1] + red[2] + red[3];
    __syncthreads();
    return v;
}

__global__ __launch_bounds__(256, 4) void fused_all(
        const float* __restrict__ x, const float* __restrict__ neg,
        float* __restrict__ out,
        float* __restrict__ pchain, float* __restrict__ pp,
        float* __restrict__ cs, float* __restrict__ sq,
        float* __restrict__ pm, float* __restrict__ pairval) {
    cg::grid_group grid = cg::this_grid();

    const int blk  = blockIdx.x;          // 0 .. GRID-1
    const int t    = threadIdx.x;
    const int wave = t >> 6;
    const int lane = t & 63;

    __shared__ float4 sacc[4][64];
    __shared__ float  sps[4];
    __shared__ float  red[4];
    __shared__ float  lnn[NNEG];
    __shared__ float  nn8[NNEG][8];

    // ================= Phase 1: per-chunk partial chain sums =================
    {
        const int b = blk / CH;
        const int c = blk % CH;
        const float* base = x + ((size_t)(b * S + c * ROWS)) * D + lane * 4;

        float4 acc = make_float4(0.f, 0.f, 0.f, 0.f);
        float  ps  = 0.f;

        for (int r = wave; r < ROWS; r += 4) {
            const float4 v = *(const float4*)(base + (size_t)r * D);
            float ss = v.x * v.x + v.y * v.y + v.z * v.z + v.w * v.w;
            #pragma unroll
            for (int m = 1; m < 64; m <<= 1) ss += __shfl_xor(ss, m, 64);
            const float inv = 1.0f / fmaxf(sqrtf(ss), EPSN);
            acc.x += v.x * inv;
            acc.y += v.y * inv;
            acc.z += v.z * inv;
            acc.w += v.w * inv;
            ps += v.x + v.y + v.z + v.w;
        }
        #pragma unroll
        for (int m = 1; m < 64; m <<= 1) ps += __shfl_xor(ps, m, 64);

        sacc[wave][lane] = acc;
        if (lane == 0) sps[wave] = ps;
        __syncthreads();

        if (wave == 0) {
            const float4 t0 = sacc[0][lane];
            const float4 t1 = sacc[1][lane];
            const float4 t2 = sacc[2][lane];
            const float4 t3 = sacc[3][lane];
            float4 o;
            o.x = t0.x + t1.x + t2.x + t3.x;
            o.y = t0.y + t1.y + t2.y + t3.y;
            o.z = t0.z + t1.z + t2.z + t3.z;
            o.w = t0.w + t1.w + t2.w + t3.w;
            *(float4*)(pchain + (size_t)blk * D + lane * 4) = o;
            if (lane == 0) pp[blk] = sps[0] + sps[1] + sps[2] + sps[3];
        }
    }
    grid.sync();

    // ================= Phase 2: chain reduce (blocks 0..B-1) =================
    if (blk < B) {
        const int b = blk;
        float v = 0.f;
        #pragma unroll
        for (int c = 0; c < CH; ++c) v += pchain[(size_t)(b * CH + c) * D + t];
        cs[b * D + t] = v;

        float s2 = v * v;
        #pragma unroll
        for (int m = 1; m < 64; m <<= 1) s2 += __shfl_xor(s2, m, 64);
        if (lane == 0) red[wave] = s2;
        __syncthreads();
        if (t == 0) {
            sq[b] = red[0] + red[1] + red[2] + red[3];
            float s = 0.f;
            #pragma unroll
            for (int c = 0; c < CH; ++c) s += pp[b * CH + c];
            pm[b] = s / (float)(S * D);
        }
    }
    grid.sync();

    // ================= Phase 3: gram pair dots, wave per (i,j) cell =========
    {
        const int wid = blk * 4 + wave;       // 0..NCELL-1
        const int i = wid >> 6, j = wid & 63;
        float v = 0.f;
        if (i < j) {
            const float4 a  = *(const float4*)(cs + (size_t)i * D + lane * 4);
            const float4 bb = *(const float4*)(cs + (size_t)j * D + lane * 4);
            float dot = a.x * bb.x + a.y * bb.y + a.z * bb.z + a.w * bb.w;
            #pragma unroll
            for (int m = 1; m < 64; m <<= 1) dot += __shfl_xor(dot, m, 64);
            const float invS2 = 1.0f / ((float)S * (float)S);
            v = fminf(dot * invS2, 1.0f);
        }
        if (lane == 0) pairval[wid] = v;      // 0 for i>=j cells
    }
    grid.sync();

    // ================= Phase 4: block 0 finalizes =================
    if (blk == 0) {
        // hard-negative row partial means: thread -> (k = t/8, part = t%8)
        {
            const int k = t >> 3, part = t & 7;
            float s = 0.f;
            #pragma unroll 8
            for (int e = 0; e < 32; ++e) s += neg[k * 256 + part * 32 + e];
            nn8[k][part] = s;
        }
        __syncthreads();
        if (t < NNEG) {
            float s = 0.f;
            #pragma unroll
            for (int e = 0; e < 8; ++e) s += nn8[t][e];
            lnn[t] = s / (float)D;
        }

        float my_inter = 0.f;
        for (int k = t; k < NCELL; k += 256) my_inter += pairval[k];

        float my_intra = 0.f;
        if (t < B) {
            const float ia = (sq[t] - (float)S) / ((float)S * (float)(S - 1));
            my_intra = fminf(ia, 1.0f);
        }
        __syncthreads();  // lnn ready

        float my_hard = 0.f;
        for (int k = t; k < B * NNEG; k += 256) {
            const int bb = k >> 5, nk = k & 31;
            my_hard += fmaxf(lnn[nk] - pm[bb] + 1.0f, 0.f);
        }

        const float intra = block_sum256(my_intra, red, wave, lane) / (float)B;
        const float inter = block_sum256(my_inter, red, wave, lane) / (float)NPAIR;
        const float hard  = block_sum256(my_hard,  red, wave, lane) / (float)(B * NNEG);

        if (t == 0) {
            out[0] = intra;
            out[1] = inter;
            out[2] = hard;
            out[3] = intra + inter + 0.1f * hard;
        }
    }
}

extern "C" void kernel_launch(void* const* d_in, const int* in_sizes, int n_in,
                              void* d_out, int out_size, void* d_ws, size_t ws_size,
                              hipStream_t stream) {
    const float* x   = (const float*)d_in[0];   // [B, S, D]
    const float* neg = (const float*)d_in[1];   // [NNEG, D]
    float* out = (float*)d_out;

    // workspace layout (floats)
    float* w = (float*)d_ws;
    float* pchain  = w;                              // GRID*D = 262144
    float* pp      = pchain + (size_t)GRID * D;      // GRID   = 1024
    float* cs      = pp + GRID;                      // B*D    = 16384
    float* sq      = cs + B * D;                     // B
    float* pm      = sq + B;                         // B
    float* pairval = pm + B;                         // NCELL  = 4096

    void* args[] = {(void*)&x, (void*)&neg, (void*)&out,
                    (void*)&pchain, (void*)&pp, (void*)&cs,
                    (void*)&sq, (void*)&pm, (void*)&pairval};
    hipLaunchCooperativeKernel((const void*)fused_all, dim3(GRID), dim3(256),
                               args, 0, stream);
}

// Round 4
// 95.525 us; speedup vs baseline: 3.2307x; 3.2307x over previous
//
#include <hip/hip_runtime.h>
#include <math.h>

// Problem constants (fixed by reference setup_inputs)
constexpr int B = 64;
constexpr int S = 1024;
constexpr int D = 256;
constexpr int NNEG = 32;
constexpr int CH = 16;                  // chunks per chain
constexpr int ROWS = S / CH;            // 64 rows per chunk block
constexpr int GRID = B * CH;            // 1024 blocks
constexpr int NPAIR = B * (B - 1) / 2;  // 2016
#define EPSN 1e-8f

__device__ __forceinline__ float block_sum256(float v, volatile float* red,
                                              int wave, int lane) {
    #pragma unroll
    for (int m = 1; m < 64; m <<= 1) v += __shfl_xor(v, m, 64);
    if (lane == 0) red[wave] = v;
    __syncthreads();
    v = red[0] + red[1] + red[2] + red[3];
    __syncthreads();
    return v;
}

// Counters in ws (ints): [0..B-1] per-chain arrival, [B] done_ctr, [B+1] fin_ctr.
// Zeroed by hipMemsetAsync before each launch (stream-ordered, graph-capturable).
__global__ __launch_bounds__(256) void fused(
        const float* __restrict__ x, const float* __restrict__ neg,
        float* __restrict__ out, int* __restrict__ ctrs,
        float* __restrict__ pchain, float* __restrict__ pp,
        float* __restrict__ cs, float* __restrict__ sq,
        float* __restrict__ pm, float* __restrict__ inter_part) {
    const int blk  = blockIdx.x;
    const int t    = threadIdx.x;
    const int wave = t >> 6;
    const int lane = t & 63;
    const int b    = blk / CH;
    const int c    = blk % CH;

    __shared__ float4 sacc[4][64];
    __shared__ float  sps[4];
    __shared__ float  red[4];
    __shared__ int    role;
    __shared__ float  lnn[NNEG];
    __shared__ float  nn8[NNEG][8];

    // ================= Phase 1: per-chunk partial chain sums =================
    {
        const float* base = x + ((size_t)(b * S + c * ROWS)) * D + lane * 4;
        float4 acc = make_float4(0.f, 0.f, 0.f, 0.f);
        float  ps  = 0.f;

        for (int r = wave; r < ROWS; r += 4) {
            const float4 v = *(const float4*)(base + (size_t)r * D);
            float ss = v.x * v.x + v.y * v.y + v.z * v.z + v.w * v.w;
            #pragma unroll
            for (int m = 1; m < 64; m <<= 1) ss += __shfl_xor(ss, m, 64);
            const float inv = 1.0f / fmaxf(sqrtf(ss), EPSN);
            acc.x += v.x * inv;
            acc.y += v.y * inv;
            acc.z += v.z * inv;
            acc.w += v.w * inv;
            ps += v.x + v.y + v.z + v.w;
        }
        #pragma unroll
        for (int m = 1; m < 64; m <<= 1) ps += __shfl_xor(ps, m, 64);

        sacc[wave][lane] = acc;
        if (lane == 0) sps[wave] = ps;
        __syncthreads();

        if (wave == 0) {
            const float4 t0 = sacc[0][lane];
            const float4 t1 = sacc[1][lane];
            const float4 t2 = sacc[2][lane];
            const float4 t3 = sacc[3][lane];
            float4 o;
            o.x = t0.x + t1.x + t2.x + t3.x;
            o.y = t0.y + t1.y + t2.y + t3.y;
            o.z = t0.z + t1.z + t2.z + t3.z;
            o.w = t0.w + t1.w + t2.w + t3.w;
            *(float4*)(pchain + (size_t)blk * D + lane * 4) = o;
            if (lane == 0) pp[blk] = sps[0] + sps[1] + sps[2] + sps[3];
        }
        __syncthreads();  // all stores issued & drained (vmcnt) before fence
        if (t == 0) {
            __threadfence();
            const int old = __hip_atomic_fetch_add(&ctrs[b], 1, __ATOMIC_ACQ_REL,
                                                   __HIP_MEMORY_SCOPE_AGENT);
            role = (old == CH - 1) ? 1 : 0;
        }
        __syncthreads();
        if (!role) return;  // 960 blocks exit; 64 chain-reducers continue
    }

    // ================= Phase 2: chain reduce (this block owns chain b) =======
    {
        float v = 0.f;
        #pragma unroll
        for (int cc = 0; cc < CH; ++cc) v += pchain[(size_t)(b * CH + cc) * D + t];
        cs[(size_t)b * D + t] = v;

        float s2 = v * v;
        #pragma unroll
        for (int m = 1; m < 64; m <<= 1) s2 += __shfl_xor(s2, m, 64);
        if (lane == 0) red[wave] = s2;
        __syncthreads();
        if (t == 0) {
            sq[b] = red[0] + red[1] + red[2] + red[3];
            float s = 0.f;
            #pragma unroll
            for (int cc = 0; cc < CH; ++cc) s += pp[b * CH + cc];
            pm[b] = s / (float)(S * D);
        }
        __syncthreads();  // drain stores; red free for reuse
        if (t == 0) {
            __threadfence();
            __hip_atomic_fetch_add(&ctrs[B], 1, __ATOMIC_ACQ_REL,
                                   __HIP_MEMORY_SCOPE_AGENT);
            // spin only AFTER own increment -> counter reaches B regardless of
            // scheduling; all 64 participants are already-executing blocks.
            while (__hip_atomic_load(&ctrs[B], __ATOMIC_ACQUIRE,
                                     __HIP_MEMORY_SCOPE_AGENT) < B) {
                __builtin_amdgcn_s_sleep(2);
            }
        }
        __syncthreads();
    }

    // ================= Phase 3: Gram row b (wave per cell j>b) ===============
    {
        const float invS2 = 1.0f / ((float)S * (float)S);
        const float4 a = *(const float4*)(cs + (size_t)b * D + lane * 4);
        float my = 0.f;
        for (int j = b + 1 + wave; j < B; j += 4) {
            const float4 bb = *(const float4*)(cs + (size_t)j * D + lane * 4);
            float dot = a.x * bb.x + a.y * bb.y + a.z * bb.z + a.w * bb.w;
            #pragma unroll
            for (int m = 1; m < 64; m <<= 1) dot += __shfl_xor(dot, m, 64);
            my += fminf(dot * invS2, 1.0f);
        }
        if (lane == 0) red[wave] = my;
        __syncthreads();
        if (t == 0) inter_part[b] = red[0] + red[1] + red[2] + red[3];
        __syncthreads();
        if (t == 0) {
            __threadfence();
            const int old = __hip_atomic_fetch_add(&ctrs[B + 1], 1, __ATOMIC_ACQ_REL,
                                                   __HIP_MEMORY_SCOPE_AGENT);
            role = (old == B - 1) ? 1 : 0;
        }
        __syncthreads();
        if (!role) return;  // last arrival finalizes
    }

    // ================= Phase 4: finalize all four losses =====================
    {
        const int k = t >> 3, part = t & 7;
        float s = 0.f;
        #pragma unroll 8
        for (int e = 0; e < 32; ++e) s += neg[k * 256 + part * 32 + e];
        nn8[k][part] = s;
    }
    __syncthreads();
    if (t < NNEG) {
        float s = 0.f;
        #pragma unroll
        for (int e = 0; e < 8; ++e) s += nn8[t][e];
        lnn[t] = s / (float)D;
    }

    float my_inter = 0.f, my_intra = 0.f;
    if (t < B) {
        my_inter = inter_part[t];
        my_intra = fminf((sq[t] - (float)S) / ((float)S * (float)(S - 1)), 1.0f);
    }
    __syncthreads();  // lnn ready

    float my_hard = 0.f;
    for (int k = t; k < B * NNEG; k += 256) {
        const int bb = k >> 5, nk = k & 31;
        my_hard += fmaxf(lnn[nk] - pm[bb] + 1.0f, 0.f);
    }

    const float intra = block_sum256(my_intra, red, wave, lane) / (float)B;
    const float inter = block_sum256(my_inter, red, wave, lane) / (float)NPAIR;
    const float hard  = block_sum256(my_hard,  red, wave, lane) / (float)(B * NNEG);

    if (t == 0) {
        out[0] = intra;
        out[1] = inter;
        out[2] = hard;
        out[3] = intra + inter + 0.1f * hard;
    }
}

extern "C" void kernel_launch(void* const* d_in, const int* in_sizes, int n_in,
                              void* d_out, int out_size, void* d_ws, size_t ws_size,
                              hipStream_t stream) {
    const float* x   = (const float*)d_in[0];   // [B, S, D]
    const float* neg = (const float*)d_in[1];   // [NNEG, D]
    float* out = (float*)d_out;

    int*   ctrs = (int*)d_ws;                        // B+2 ints, reset below
    float* wf   = (float*)((char*)d_ws + 512);       // 16B-aligned float region
    float* pchain     = wf;                          // GRID*D = 262144
    float* pp         = pchain + (size_t)GRID * D;   // GRID
    float* cs         = pp + GRID;                   // B*D
    float* sq         = cs + B * D;                  // B
    float* pm         = sq + B;                      // B
    float* inter_part = pm + B;                      // B

    hipMemsetAsync(d_ws, 0, 512, stream);            // zero counters (captured)
    fused<<<GRID, 256, 0, stream>>>(x, neg, out, ctrs, pchain, pp,
                                    cs, sq, pm, inter_part);
}

// Round 5
// 47.848 us; speedup vs baseline: 6.4498x; 1.9964x over previous
//
#include <hip/hip_runtime.h>
#include <math.h>

// Problem constants (fixed by reference setup_inputs)
constexpr int B = 64;
constexpr int S = 1024;
constexpr int D = 256;
constexpr int NNEG = 32;
constexpr int NPAIR = B * (B - 1) / 2;  // 2016
#define EPSN 1e-8f

// ================= K1: one fat block per chain =================
// Blocks 0..63: chain b (1024 rows x 256). 16 waves x 64 rows, 4-row unroll.
// Block 64: hard-negative row means (32 rows x 256).
__global__ __launch_bounds__(1024) void k1_chain(const float* __restrict__ x,
                                                 const float* __restrict__ neg,
                                                 float* __restrict__ cs,
                                                 float* __restrict__ sq,
                                                 float* __restrict__ pm,
                                                 float* __restrict__ lnn) {
    const int blk  = blockIdx.x;
    const int t    = threadIdx.x;
    const int wave = t >> 6;   // 0..15
    const int lane = t & 63;

    if (blk == B) {
        // negative means: thread t -> row k = t/32, part p = t%32, 8 elems each
        const int k = t >> 5, p = t & 31;
        const float4 v0 = *(const float4*)(neg + k * D + p * 8);
        const float4 v1 = *(const float4*)(neg + k * D + p * 8 + 4);
        float s = v0.x + v0.y + v0.z + v0.w + v1.x + v1.y + v1.z + v1.w;
        #pragma unroll
        for (int m = 1; m < 32; m <<= 1) s += __shfl_xor(s, m, 64);
        if (p == 0) lnn[k] = s * (1.0f / (float)D);
        return;
    }

    constexpr int WP = D + 4;          // padded LDS row: bank varies with wave
    __shared__ float sacc[16][WP];     // ~16.6 KB
    __shared__ float sps[16];
    __shared__ float red[16];

    // wave handles rows [wave*64, wave*64+64)
    const float* rowp = x + (size_t)blk * S * D + (size_t)(wave * 64) * D + lane * 4;

    float ax = 0.f, ay = 0.f, az = 0.f, aw = 0.f, ps = 0.f;
    for (int i = 0; i < 64; i += 4) {
        const float4 v0 = *(const float4*)(rowp + (size_t)(i + 0) * D);
        const float4 v1 = *(const float4*)(rowp + (size_t)(i + 1) * D);
        const float4 v2 = *(const float4*)(rowp + (size_t)(i + 2) * D);
        const float4 v3 = *(const float4*)(rowp + (size_t)(i + 3) * D);

        float s0 = v0.x * v0.x + v0.y * v0.y + v0.z * v0.z + v0.w * v0.w;
        float s1 = v1.x * v1.x + v1.y * v1.y + v1.z * v1.z + v1.w * v1.w;
        float s2 = v2.x * v2.x + v2.y * v2.y + v2.z * v2.z + v2.w * v2.w;
        float s3 = v3.x * v3.x + v3.y * v3.y + v3.z * v3.z + v3.w * v3.w;
        #pragma unroll
        for (int m = 1; m < 64; m <<= 1) {
            s0 += __shfl_xor(s0, m, 64);
            s1 += __shfl_xor(s1, m, 64);
            s2 += __shfl_xor(s2, m, 64);
            s3 += __shfl_xor(s3, m, 64);
        }
        const float i0 = 1.0f / fmaxf(sqrtf(s0), EPSN);
        const float i1 = 1.0f / fmaxf(sqrtf(s1), EPSN);
        const float i2 = 1.0f / fmaxf(sqrtf(s2), EPSN);
        const float i3 = 1.0f / fmaxf(sqrtf(s3), EPSN);

        ax += v0.x * i0 + v1.x * i1 + v2.x * i2 + v3.x * i3;
        ay += v0.y * i0 + v1.y * i1 + v2.y * i2 + v3.y * i3;
        az += v0.z * i0 + v1.z * i1 + v2.z * i2 + v3.z * i3;
        aw += v0.w * i0 + v1.w * i1 + v2.w * i2 + v3.w * i3;
        ps += (v0.x + v0.y + v0.z + v0.w) + (v1.x + v1.y + v1.z + v1.w) +
              (v2.x + v2.y + v2.z + v2.w) + (v3.x + v3.y + v3.z + v3.w);
    }

    *(float4*)&sacc[wave][lane * 4] = make_float4(ax, ay, az, aw);
    #pragma unroll
    for (int m = 1; m < 64; m <<= 1) ps += __shfl_xor(ps, m, 64);
    if (lane == 0) sps[wave] = ps;
    __syncthreads();

    if (t < D) {
        float v = 0.f;
        #pragma unroll
        for (int w = 0; w < 16; ++w) v += sacc[w][t];  // bank=(4w+t)%32: no conflict pileup
        cs[(size_t)blk * D + t] = v;
        float s2 = v * v;
        #pragma unroll
        for (int m = 1; m < 64; m <<= 1) s2 += __shfl_xor(s2, m, 64);
        if (lane == 0) red[wave] = s2;
    }
    __syncthreads();
    if (t == 0) {
        sq[blk] = red[0] + red[1] + red[2] + red[3];
        float s = 0.f;
        #pragma unroll
        for (int w = 0; w < 16; ++w) s += sps[w];
        pm[blk] = s / (float)(S * D);
    }
}

// ================= K2: Gram rows + last-block finalize =================
__device__ __forceinline__ float block_sum256(float v, volatile float* red,
                                              int wave, int lane) {
    #pragma unroll
    for (int m = 1; m < 64; m <<= 1) v += __shfl_xor(v, m, 64);
    if (lane == 0) red[wave] = v;
    __syncthreads();
    v = red[0] + red[1] + red[2] + red[3];
    __syncthreads();
    return v;
}

__global__ __launch_bounds__(256) void k2_gram(const float* __restrict__ cs,
                                               const float* __restrict__ sq,
                                               const float* __restrict__ pm,
                                               const float* __restrict__ lnn,
                                               float* __restrict__ inter_part,
                                               int* __restrict__ ctr,
                                               float* __restrict__ out) {
    const int b    = blockIdx.x;
    const int t    = threadIdx.x;
    const int wave = t >> 6;
    const int lane = t & 63;

    __shared__ float red[4];
    __shared__ int   role;

    // Gram row b: waves stride over columns j > b
    {
        const float invS2 = 1.0f / ((float)S * (float)S);
        const float4 a = *(const float4*)(cs + (size_t)b * D + lane * 4);
        float my = 0.f;
        for (int j = b + 1 + wave; j < B; j += 4) {
            const float4 bb = *(const float4*)(cs + (size_t)j * D + lane * 4);
            float dot = a.x * bb.x + a.y * bb.y + a.z * bb.z + a.w * bb.w;
            #pragma unroll
            for (int m = 1; m < 64; m <<= 1) dot += __shfl_xor(dot, m, 64);
            my += fminf(dot * invS2, 1.0f);
        }
        if (lane == 0) red[wave] = my;
        __syncthreads();
        if (t == 0) inter_part[b] = red[0] + red[1] + red[2] + red[3];
        __syncthreads();
    }

    // last-block handoff (single atomic per block, no spin)
    if (t == 0) {
        __threadfence();  // release our inter_part store device-wide
        const int old = __hip_atomic_fetch_add(ctr, 1, __ATOMIC_ACQ_REL,
                                               __HIP_MEMORY_SCOPE_AGENT);
        role = (old == B - 1) ? 1 : 0;
    }
    __syncthreads();
    if (!role) return;

    // ---- finalize (winner block only) ----
    float my_inter = 0.f, my_intra = 0.f;
    if (t < B) {
        my_inter = inter_part[t];
        my_intra = fminf((sq[t] - (float)S) / ((float)S * (float)(S - 1)), 1.0f);
    }

    float my_hard = 0.f;
    for (int k = t; k < B * NNEG; k += 256) {
        const int bb = k >> 5, nk = k & 31;
        my_hard += fmaxf(lnn[nk] - pm[bb] + 1.0f, 0.f);
    }

    const float intra = block_sum256(my_intra, red, wave, lane) / (float)B;
    const float inter = block_sum256(my_inter, red, wave, lane) / (float)NPAIR;
    const float hard  = block_sum256(my_hard,  red, wave, lane) / (float)(B * NNEG);

    if (t == 0) {
        out[0] = intra;
        out[1] = inter;
        out[2] = hard;
        out[3] = intra + inter + 0.1f * hard;
    }
}

extern "C" void kernel_launch(void* const* d_in, const int* in_sizes, int n_in,
                              void* d_out, int out_size, void* d_ws, size_t ws_size,
                              hipStream_t stream) {
    const float* x   = (const float*)d_in[0];   // [B, S, D]
    const float* neg = (const float*)d_in[1];   // [NNEG, D]
    float* out = (float*)d_out;

    int*   ctr = (int*)d_ws;                     // one counter (reset below)
    float* wf  = (float*)((char*)d_ws + 512);
    float* cs         = wf;                      // B*D = 16384
    float* sq         = cs + B * D;              // B
    float* pm         = sq + B;                  // B
    float* lnn        = pm + B;                  // NNEG
    float* inter_part = lnn + NNEG;              // B

    hipMemsetAsync(d_ws, 0, 64, stream);         // zero counter (stream-ordered)
    k1_chain<<<B + 1, 1024, 0, stream>>>(x, neg, cs, sq, pm, lnn);
    k2_gram<<<B, 256, 0, stream>>>(cs, sq, pm, lnn, inter_part, ctr, out);
}

// Round 6
// 45.303 us; speedup vs baseline: 6.8121x; 1.0562x over previous
//
#include <hip/hip_runtime.h>
#include <math.h>

// Problem constants (fixed by reference setup_inputs)
constexpr int B = 64;
constexpr int S = 1024;
constexpr int D = 256;
constexpr int NNEG = 32;
constexpr int Q = 4;                    // quarter-chunks per chain
constexpr int GRID1 = B * Q;            // 256 blocks -> 1 per CU
constexpr int RPB = S / Q;              // 256 rows per K1 block
constexpr int NPAIR = B * (B - 1) / 2;  // 2016
#define EPSN 1e-8f

// ================= K1: quarter-chain partial sums, full-machine width =========
// 256 blocks x 1024 thr (16 waves). Wave w: rows [w*16, w*16+16) of the quarter.
__global__ __launch_bounds__(1024) void k1(const float* __restrict__ x,
                                           float* __restrict__ pchain,
                                           float* __restrict__ pp) {
    const int blk  = blockIdx.x;        // chain b = blk/Q, quarter q = blk%Q
    const int t    = threadIdx.x;
    const int wave = t >> 6;            // 0..15
    const int lane = t & 63;

    __shared__ float sacc[16][D + 4];   // ~16.6 KB, bank-safe column reduce
    __shared__ float sps[16];

    const float* rowp = x + (size_t)blk * RPB * D + (size_t)(wave * 16) * D + lane * 4;

    float ax = 0.f, ay = 0.f, az = 0.f, aw = 0.f, ps = 0.f;
    #pragma unroll
    for (int i = 0; i < 16; i += 4) {
        const float4 v0 = *(const float4*)(rowp + (size_t)(i + 0) * D);
        const float4 v1 = *(const float4*)(rowp + (size_t)(i + 1) * D);
        const float4 v2 = *(const float4*)(rowp + (size_t)(i + 2) * D);
        const float4 v3 = *(const float4*)(rowp + (size_t)(i + 3) * D);

        float s0 = v0.x * v0.x + v0.y * v0.y + v0.z * v0.z + v0.w * v0.w;
        float s1 = v1.x * v1.x + v1.y * v1.y + v1.z * v1.z + v1.w * v1.w;
        float s2 = v2.x * v2.x + v2.y * v2.y + v2.z * v2.z + v2.w * v2.w;
        float s3 = v3.x * v3.x + v3.y * v3.y + v3.z * v3.z + v3.w * v3.w;
        #pragma unroll
        for (int m = 1; m < 64; m <<= 1) {
            s0 += __shfl_xor(s0, m, 64);
            s1 += __shfl_xor(s1, m, 64);
            s2 += __shfl_xor(s2, m, 64);
            s3 += __shfl_xor(s3, m, 64);
        }
        const float i0 = 1.0f / fmaxf(sqrtf(s0), EPSN);
        const float i1 = 1.0f / fmaxf(sqrtf(s1), EPSN);
        const float i2 = 1.0f / fmaxf(sqrtf(s2), EPSN);
        const float i3 = 1.0f / fmaxf(sqrtf(s3), EPSN);

        ax += v0.x * i0 + v1.x * i1 + v2.x * i2 + v3.x * i3;
        ay += v0.y * i0 + v1.y * i1 + v2.y * i2 + v3.y * i3;
        az += v0.z * i0 + v1.z * i1 + v2.z * i2 + v3.z * i3;
        aw += v0.w * i0 + v1.w * i1 + v2.w * i2 + v3.w * i3;
        ps += (v0.x + v0.y + v0.z + v0.w) + (v1.x + v1.y + v1.z + v1.w) +
              (v2.x + v2.y + v2.z + v2.w) + (v3.x + v3.y + v3.z + v3.w);
    }

    *(float4*)&sacc[wave][lane * 4] = make_float4(ax, ay, az, aw);
    #pragma unroll
    for (int m = 1; m < 64; m <<= 1) ps += __shfl_xor(ps, m, 64);
    if (lane == 0) sps[wave] = ps;
    __syncthreads();

    if (t < D) {
        float v = 0.f;
        #pragma unroll
        for (int w = 0; w < 16; ++w) v += sacc[w][t];  // bank (4w+t)%32 varies
        pchain[(size_t)blk * D + t] = v;
    }
    if (t == 0) {
        float s = 0.f;
        #pragma unroll
        for (int w = 0; w < 16; ++w) s += sps[w];
        pp[blk] = s;
    }
}

// ================= K2: per-block full chain-sum rebuild + gram row ============
// 64 blocks x 256 thr. Thread t owns dim t; cs[] register array, static index only.
__global__ __launch_bounds__(256) void k2(const float* __restrict__ pchain,
                                          const float* __restrict__ pp,
                                          const float* __restrict__ neg,
                                          float* __restrict__ inter_part,
                                          float* __restrict__ scal) {
    const int b    = blockIdx.x;
    const int t    = threadIdx.x;
    const int wave = t >> 6;
    const int lane = t & 63;

    __shared__ float spart[4][16], gpart[4][16];
    __shared__ float sqv[B], gv[B];
    __shared__ float red[4];
    __shared__ float pmv[B], lnnv[NNEG];
    __shared__ float nn8[NNEG][8];

    // rebuild all 64 chain sums for this thread's dim (coalesced; 256KB L2-hot)
    float cs[B];
    #pragma unroll
    for (int j = 0; j < B; ++j) {
        const float* p = pchain + (size_t)(j * Q) * D + t;
        cs[j] = p[0] + p[D] + p[2 * D] + p[3 * D];
    }
    // runtime-b value: reload from memory (avoids dynamic reg-array index -> scratch)
    const float* pb = pchain + (size_t)(b * Q) * D + t;
    const float csb = pb[0] + pb[D] + pb[2 * D] + pb[3 * D];

    // batched cross-thread reduces: sq[j] = ||cs_j||^2, gdot[j] = cs_b . cs_j
    #pragma unroll
    for (int batch = 0; batch < 4; ++batch) {
        #pragma unroll
        for (int jj = 0; jj < 16; ++jj) {
            const int j = batch * 16 + jj;
            float sv  = cs[j] * cs[j];
            float gvv = csb * cs[j];
            #pragma unroll
            for (int m = 1; m < 64; m <<= 1) {
                sv  += __shfl_xor(sv, m, 64);
                gvv += __shfl_xor(gvv, m, 64);
            }
            if (lane == 0) { spart[wave][jj] = sv; gpart[wave][jj] = gvv; }
        }
        __syncthreads();
        if (t < 16) {
            sqv[batch * 16 + t] = spart[0][t] + spart[1][t] + spart[2][t] + spart[3][t];
            gv[batch * 16 + t]  = gpart[0][t] + gpart[1][t] + gpart[2][t] + gpart[3][t];
        }
        __syncthreads();
    }

    // inter_part[b] = sum_{j>b} min(gdot[j]/S^2, 1)
    if (wave == 0) {
        const float invS2 = 1.0f / ((float)S * (float)S);
        float v = (lane > b) ? fminf(gv[lane] * invS2, 1.0f) : 0.f;
        #pragma unroll
        for (int m = 1; m < 64; m <<= 1) v += __shfl_xor(v, m, 64);
        if (lane == 0) inter_part[b] = v;
    }

    if (b == 63) {  // intra (this block's gram row is empty)
        if (wave == 1) {
            float v = fminf((sqv[lane] - (float)S) / ((float)S * (float)(S - 1)), 1.0f);
            #pragma unroll
            for (int m = 1; m < 64; m <<= 1) v += __shfl_xor(v, m, 64);
            if (lane == 0) scal[0] = v / (float)B;
        }
    }

    if (b == 62) {  // hard-negative loss (this block's gram row is 1 column)
        if (t < B) {
            const float* q = pp + t * 4;
            pmv[t] = (q[0] + q[1] + q[2] + q[3]) / (float)(S * D);
        }
        {
            const int k = t >> 3, part = t & 7;
            const float4* p4 = (const float4*)(neg + k * D + part * 32);
            float s = 0.f;
            #pragma unroll
            for (int e = 0; e < 8; ++e) {
                const float4 v = p4[e];
                s += v.x + v.y + v.z + v.w;
            }
            nn8[k][part] = s;
        }
        __syncthreads();
        if (t < NNEG) {
            float s = 0.f;
            #pragma unroll
            for (int e = 0; e < 8; ++e) s += nn8[t][e];
            lnnv[t] = s / (float)D;
        }
        __syncthreads();
        float h = 0.f;
        for (int k = t; k < B * NNEG; k += 256)
            h += fmaxf(lnnv[k & 31] - pmv[k >> 5] + 1.0f, 0.f);
        #pragma unroll
        for (int m = 1; m < 64; m <<= 1) h += __shfl_xor(h, m, 64);
        if (lane == 0) red[wave] = h;
        __syncthreads();
        if (t == 0) scal[1] = (red[0] + red[1] + red[2] + red[3]) / (float)(B * NNEG);
    }
}

// ================= K3: one wave combines =====================================
__global__ __launch_bounds__(64) void k3(const float* __restrict__ inter_part,
                                         const float* __restrict__ scal,
                                         float* __restrict__ out) {
    const int lane = threadIdx.x & 63;
    float v = inter_part[lane];
    #pragma unroll
    for (int m = 1; m < 64; m <<= 1) v += __shfl_xor(v, m, 64);
    if (lane == 0) {
        const float inter = v / (float)NPAIR;
        const float intra = scal[0];
        const float hard  = scal[1];
        out[0] = intra;
        out[1] = inter;
        out[2] = hard;
        out[3] = intra + inter + 0.1f * hard;
    }
}

extern "C" void kernel_launch(void* const* d_in, const int* in_sizes, int n_in,
                              void* d_out, int out_size, void* d_ws, size_t ws_size,
                              hipStream_t stream) {
    const float* x   = (const float*)d_in[0];   // [B, S, D]
    const float* neg = (const float*)d_in[1];   // [NNEG, D]
    float* out = (float*)d_out;

    float* wf = (float*)d_ws;
    float* pchain     = wf;                          // GRID1*D = 65536
    float* pp         = pchain + (size_t)GRID1 * D;  // GRID1   = 256
    float* inter_part = pp + GRID1;                  // B
    float* scal       = inter_part + B;              // 2

    k1<<<GRID1, 1024, 0, stream>>>(x, pchain, pp);
    k2<<<B, 256, 0, stream>>>(pchain, pp, neg, inter_part, scal);
    k3<<<1, 64, 0, stream>>>(inter_part, scal, out);
}

// Round 7
// 30.085 us; speedup vs baseline: 10.2579x; 1.5058x over previous
//
#include <hip/hip_runtime.h>
#include <math.h>

// Problem constants (fixed by reference setup_inputs)
constexpr int B = 64;
constexpr int S = 1024;
constexpr int D = 256;
constexpr int NNEG = 32;
constexpr int GPB = 32;                 // groups (blocks) per chain in K1
constexpr int G1 = B * GPB;             // 2048 partial blocks
constexpr int RPB = S / GPB;            // 32 rows per K1 block
constexpr int NPAIR = B * (B - 1) / 2;  // 2016
#define EPSN 1e-8f

// ================= K1: 32-row partial sums, fine-grained full width ==========
// 2048 blocks x 256 thr (4 waves). Wave w: 8 rows, 4-row unroll x2.
// Block 2048: hard-negative row means.
__global__ __launch_bounds__(256) void k1(const float* __restrict__ x,
                                          const float* __restrict__ neg,
                                          float* __restrict__ pblk,
                                          float* __restrict__ praw,
                                          float* __restrict__ lnn) {
    const int blk  = blockIdx.x;
    const int t    = threadIdx.x;
    const int wave = t >> 6;            // 0..3
    const int lane = t & 63;

    if (blk == G1) {
        __shared__ float nn8[NNEG][8];
        const int k = t >> 3, part = t & 7;   // 32 rows x 8 parts
        const float4* p4 = (const float4*)(neg + k * D + part * 32);
        float s = 0.f;
        #pragma unroll
        for (int e = 0; e < 8; ++e) {
            const float4 v = p4[e];
            s += v.x + v.y + v.z + v.w;
        }
        nn8[k][part] = s;
        __syncthreads();
        if (t < NNEG) {
            float ss = 0.f;
            #pragma unroll
            for (int e = 0; e < 8; ++e) ss += nn8[t][e];
            lnn[t] = ss / (float)D;
        }
        return;
    }

    __shared__ float sacc[4][D + 4];
    __shared__ float sps[4];

    const int b = blk >> 5;             // chain
    const int g = blk & 31;             // group of 32 rows
    const float* rowp = x + ((size_t)b * S + (size_t)g * RPB + wave * 8) * D + lane * 4;

    float ax = 0.f, ay = 0.f, az = 0.f, aw = 0.f, ps = 0.f;
    #pragma unroll
    for (int i = 0; i < 8; i += 4) {
        const float4 v0 = *(const float4*)(rowp + (size_t)(i + 0) * D);
        const float4 v1 = *(const float4*)(rowp + (size_t)(i + 1) * D);
        const float4 v2 = *(const float4*)(rowp + (size_t)(i + 2) * D);
        const float4 v3 = *(const float4*)(rowp + (size_t)(i + 3) * D);

        float s0 = v0.x * v0.x + v0.y * v0.y + v0.z * v0.z + v0.w * v0.w;
        float s1 = v1.x * v1.x + v1.y * v1.y + v1.z * v1.z + v1.w * v1.w;
        float s2 = v2.x * v2.x + v2.y * v2.y + v2.z * v2.z + v2.w * v2.w;
        float s3 = v3.x * v3.x + v3.y * v3.y + v3.z * v3.z + v3.w * v3.w;
        #pragma unroll
        for (int m = 1; m < 64; m <<= 1) {
            s0 += __shfl_xor(s0, m, 64);
            s1 += __shfl_xor(s1, m, 64);
            s2 += __shfl_xor(s2, m, 64);
            s3 += __shfl_xor(s3, m, 64);
        }
        const float i0 = 1.0f / fmaxf(sqrtf(s0), EPSN);
        const float i1 = 1.0f / fmaxf(sqrtf(s1), EPSN);
        const float i2 = 1.0f / fmaxf(sqrtf(s2), EPSN);
        const float i3 = 1.0f / fmaxf(sqrtf(s3), EPSN);

        ax += v0.x * i0 + v1.x * i1 + v2.x * i2 + v3.x * i3;
        ay += v0.y * i0 + v1.y * i1 + v2.y * i2 + v3.y * i3;
        az += v0.z * i0 + v1.z * i1 + v2.z * i2 + v3.z * i3;
        aw += v0.w * i0 + v1.w * i1 + v2.w * i2 + v3.w * i3;
        ps += (v0.x + v0.y + v0.z + v0.w) + (v1.x + v1.y + v1.z + v1.w) +
              (v2.x + v2.y + v2.z + v2.w) + (v3.x + v3.y + v3.z + v3.w);
    }

    *(float4*)&sacc[wave][lane * 4] = make_float4(ax, ay, az, aw);
    #pragma unroll
    for (int m = 1; m < 64; m <<= 1) ps += __shfl_xor(ps, m, 64);
    if (lane == 0) sps[wave] = ps;
    __syncthreads();

    {
        const float v = sacc[0][t] + sacc[1][t] + sacc[2][t] + sacc[3][t];
        pblk[(size_t)blk * D + t] = v;
    }
    if (t == 0) praw[blk] = sps[0] + sps[1] + sps[2] + sps[3];
}

// ================= K1b: chain reduce -> cs, sq, pm ===========================
// 64 blocks x 256 thr; thread t = dim t.
__global__ __launch_bounds__(256) void k1b(const float* __restrict__ pblk,
                                           const float* __restrict__ praw,
                                           float* __restrict__ cs,
                                           float* __restrict__ sq,
                                           float* __restrict__ pm) {
    const int b    = blockIdx.x;
    const int t    = threadIdx.x;
    const int wave = t >> 6;
    const int lane = t & 63;

    __shared__ float red[4];

    float v = 0.f;
    #pragma unroll
    for (int g = 0; g < GPB; ++g) v += pblk[(size_t)(b * GPB + g) * D + t];
    cs[(size_t)b * D + t] = v;

    float s2 = v * v;
    #pragma unroll
    for (int m = 1; m < 64; m <<= 1) s2 += __shfl_xor(s2, m, 64);
    if (lane == 0) red[wave] = s2;
    __syncthreads();
    if (t == 0) sq[b] = red[0] + red[1] + red[2] + red[3];

    if (wave == 0) {
        float s = (lane < GPB) ? praw[b * GPB + lane] : 0.f;
        #pragma unroll
        for (int m = 1; m < 32; m <<= 1) s += __shfl_xor(s, m, 64);
        if (lane == 0) pm[b] = s / (float)(S * D);
    }
}

// ================= K2: Gram row b -> inter_part[b] ===========================
__global__ __launch_bounds__(256) void k2_gram(const float* __restrict__ cs,
                                               float* __restrict__ inter_part) {
    const int b    = blockIdx.x;
    const int t    = threadIdx.x;
    const int wave = t >> 6;
    const int lane = t & 63;

    __shared__ float red[4];

    const float invS2 = 1.0f / ((float)S * (float)S);
    const float4 a = *(const float4*)(cs + (size_t)b * D + lane * 4);
    float my = 0.f;
    for (int j = b + 1 + wave; j < B; j += 4) {
        const float4 bb = *(const float4*)(cs + (size_t)j * D + lane * 4);
        float dot = a.x * bb.x + a.y * bb.y + a.z * bb.z + a.w * bb.w;
        #pragma unroll
        for (int m = 1; m < 64; m <<= 1) dot += __shfl_xor(dot, m, 64);
        my += fminf(dot * invS2, 1.0f);
    }
    if (lane == 0) red[wave] = my;
    __syncthreads();
    if (t == 0) inter_part[b] = red[0] + red[1] + red[2] + red[3];
}

// ================= K3: finalize all four losses ==============================
__device__ __forceinline__ float block_sum256(float v, volatile float* red,
                                              int wave, int lane) {
    #pragma unroll
    for (int m = 1; m < 64; m <<= 1) v += __shfl_xor(v, m, 64);
    if (lane == 0) red[wave] = v;
    __syncthreads();
    v = red[0] + red[1] + red[2] + red[3];
    __syncthreads();
    return v;
}

__global__ __launch_bounds__(256) void k3(const float* __restrict__ inter_part,
                                          const float* __restrict__ sq,
                                          const float* __restrict__ pm,
                                          const float* __restrict__ lnn,
                                          float* __restrict__ out) {
    const int t    = threadIdx.x;
    const int wave = t >> 6;
    const int lane = t & 63;

    __shared__ float red[4];

    float my_inter = 0.f, my_intra = 0.f;
    if (t < B) {
        my_inter = inter_part[t];
        my_intra = fminf((sq[t] - (float)S) / ((float)S * (float)(S - 1)), 1.0f);
    }

    float my_hard = 0.f;
    for (int k = t; k < B * NNEG; k += 256) {
        const int bb = k >> 5, nk = k & 31;
        my_hard += fmaxf(lnn[nk] - pm[bb] + 1.0f, 0.f);
    }

    const float intra = block_sum256(my_intra, red, wave, lane) / (float)B;
    const float inter = block_sum256(my_inter, red, wave, lane) / (float)NPAIR;
    const float hard  = block_sum256(my_hard,  red, wave, lane) / (float)(B * NNEG);

    if (t == 0) {
        out[0] = intra;
        out[1] = inter;
        out[2] = hard;
        out[3] = intra + inter + 0.1f * hard;
    }
}

extern "C" void kernel_launch(void* const* d_in, const int* in_sizes, int n_in,
                              void* d_out, int out_size, void* d_ws, size_t ws_size,
                              hipStream_t stream) {
    const float* x   = (const float*)d_in[0];   // [B, S, D]
    const float* neg = (const float*)d_in[1];   // [NNEG, D]
    float* out = (float*)d_out;

    float* wf = (float*)d_ws;
    float* pblk       = wf;                          // G1*D = 524288
    float* praw       = pblk + (size_t)G1 * D;       // G1
    float* cs         = praw + G1;                   // B*D
    float* sq         = cs + (size_t)B * D;          // B
    float* pm         = sq + B;                      // B
    float* lnn        = pm + B;                      // NNEG
    float* inter_part = lnn + NNEG;                  // B

    k1<<<G1 + 1, 256, 0, stream>>>(x, neg, pblk, praw, lnn);
    k1b<<<B, 256, 0, stream>>>(pblk, praw, cs, sq, pm);
    k2_gram<<<B, 256, 0, stream>>>(cs, inter_part);
    k3<<<1, 256, 0, stream>>>(inter_part, sq, pm, lnn, out);
}

// Round 8
// 29.622 us; speedup vs baseline: 10.4183x; 1.0156x over previous
//
#include <hip/hip_runtime.h>
#include <math.h>

// Problem constants (fixed by reference setup_inputs)
constexpr int B = 64;
constexpr int S = 1024;
constexpr int D = 256;
constexpr int NNEG = 32;
constexpr int GPB = 32;                 // groups (blocks) per chain in K1
constexpr int G1 = B * GPB;             // 2048 partial blocks
constexpr int RPB = S / GPB;            // 32 rows per K1 block
constexpr int NPAIR = B * (B - 1) / 2;  // 2016

// ================= K1: 32-row partial sums, fine-grained full width ==========
// 2048 blocks x 256 thr (4 waves). Wave w: 8 rows, 4-row unroll x2.
// Block 2048: hard-negative row means + zeroes the k2fin counter.
__global__ __launch_bounds__(256) void k1(const float* __restrict__ x,
                                          const float* __restrict__ neg,
                                          float* __restrict__ pblk,
                                          float* __restrict__ praw,
                                          float* __restrict__ lnn,
                                          int* __restrict__ ctr) {
    const int blk  = blockIdx.x;
    const int t    = threadIdx.x;
    const int wave = t >> 6;            // 0..3
    const int lane = t & 63;

    if (blk == G1) {
        __shared__ float nn8[NNEG][8];
        if (t == 0) ctr[0] = 0;               // reset k2fin's arrival counter
        const int k = t >> 3, part = t & 7;   // 32 rows x 8 parts
        const float4* p4 = (const float4*)(neg + k * D + part * 32);
        float s = 0.f;
        #pragma unroll
        for (int e = 0; e < 8; ++e) {
            const float4 v = p4[e];
            s += v.x + v.y + v.z + v.w;
        }
        nn8[k][part] = s;
        __syncthreads();
        if (t < NNEG) {
            float ss = 0.f;
            #pragma unroll
            for (int e = 0; e < 8; ++e) ss += nn8[t][e];
            lnn[t] = ss / (float)D;
        }
        return;
    }

    __shared__ float sacc[4][D + 4];
    __shared__ float sps[4];

    const int b = blk >> 5;             // chain
    const int g = blk & 31;             // group of 32 rows
    const float* rowp = x + ((size_t)b * S + (size_t)g * RPB + wave * 8) * D + lane * 4;

    float ax = 0.f, ay = 0.f, az = 0.f, aw = 0.f, ps = 0.f;
    #pragma unroll
    for (int i = 0; i < 8; i += 4) {
        const float4 v0 = *(const float4*)(rowp + (size_t)(i + 0) * D);
        const float4 v1 = *(const float4*)(rowp + (size_t)(i + 1) * D);
        const float4 v2 = *(const float4*)(rowp + (size_t)(i + 2) * D);
        const float4 v3 = *(const float4*)(rowp + (size_t)(i + 3) * D);

        float s0 = v0.x * v0.x + v0.y * v0.y + v0.z * v0.z + v0.w * v0.w;
        float s1 = v1.x * v1.x + v1.y * v1.y + v1.z * v1.z + v1.w * v1.w;
        float s2 = v2.x * v2.x + v2.y * v2.y + v2.z * v2.z + v2.w * v2.w;
        float s3 = v3.x * v3.x + v3.y * v3.y + v3.z * v3.z + v3.w * v3.w;
        #pragma unroll
        for (int m = 1; m < 64; m <<= 1) {
            s0 += __shfl_xor(s0, m, 64);
            s1 += __shfl_xor(s1, m, 64);
            s2 += __shfl_xor(s2, m, 64);
            s3 += __shfl_xor(s3, m, 64);
        }
        // 1/max(sqrt(ss),1e-8) == rsq(max(ss,1e-16)); single v_rsq_f32
        const float i0 = __builtin_amdgcn_rsqf(fmaxf(s0, 1e-16f));
        const float i1 = __builtin_amdgcn_rsqf(fmaxf(s1, 1e-16f));
        const float i2 = __builtin_amdgcn_rsqf(fmaxf(s2, 1e-16f));
        const float i3 = __builtin_amdgcn_rsqf(fmaxf(s3, 1e-16f));

        ax += v0.x * i0 + v1.x * i1 + v2.x * i2 + v3.x * i3;
        ay += v0.y * i0 + v1.y * i1 + v2.y * i2 + v3.y * i3;
        az += v0.z * i0 + v1.z * i1 + v2.z * i2 + v3.z * i3;
        aw += v0.w * i0 + v1.w * i1 + v2.w * i2 + v3.w * i3;
        ps += (v0.x + v0.y + v0.z + v0.w) + (v1.x + v1.y + v1.z + v1.w) +
              (v2.x + v2.y + v2.z + v2.w) + (v3.x + v3.y + v3.z + v3.w);
    }

    *(float4*)&sacc[wave][lane * 4] = make_float4(ax, ay, az, aw);
    #pragma unroll
    for (int m = 1; m < 64; m <<= 1) ps += __shfl_xor(ps, m, 64);
    if (lane == 0) sps[wave] = ps;
    __syncthreads();

    {
        const float v = sacc[0][t] + sacc[1][t] + sacc[2][t] + sacc[3][t];
        pblk[(size_t)blk * D + t] = v;
    }
    if (t == 0) praw[blk] = sps[0] + sps[1] + sps[2] + sps[3];
}

// ================= K1b: chain reduce -> cs, sq, pm ===========================
// 64 blocks x 256 thr; thread t = dim t.
__global__ __launch_bounds__(256) void k1b(const float* __restrict__ pblk,
                                           const float* __restrict__ praw,
                                           float* __restrict__ cs,
                                           float* __restrict__ sq,
                                           float* __restrict__ pm) {
    const int b    = blockIdx.x;
    const int t    = threadIdx.x;
    const int wave = t >> 6;
    const int lane = t & 63;

    __shared__ float red[4];

    float v = 0.f;
    #pragma unroll
    for (int g = 0; g < GPB; ++g) v += pblk[(size_t)(b * GPB + g) * D + t];
    cs[(size_t)b * D + t] = v;

    float s2 = v * v;
    #pragma unroll
    for (int m = 1; m < 64; m <<= 1) s2 += __shfl_xor(s2, m, 64);
    if (lane == 0) red[wave] = s2;
    __syncthreads();
    if (t == 0) sq[b] = red[0] + red[1] + red[2] + red[3];

    if (wave == 0) {
        float s = (lane < GPB) ? praw[b * GPB + lane] : 0.f;
        #pragma unroll
        for (int m = 1; m < 32; m <<= 1) s += __shfl_xor(s, m, 64);
        if (lane == 0) pm[b] = s / (float)(S * D);
    }
}

// ================= K2fin: Gram row + last-block finalize =====================
__device__ __forceinline__ float block_sum256(float v, volatile float* red,
                                              int wave, int lane) {
    #pragma unroll
    for (int m = 1; m < 64; m <<= 1) v += __shfl_xor(v, m, 64);
    if (lane == 0) red[wave] = v;
    __syncthreads();
    v = red[0] + red[1] + red[2] + red[3];
    __syncthreads();
    return v;
}

__global__ __launch_bounds__(256) void k2fin(const float* __restrict__ cs,
                                             const float* __restrict__ sq,
                                             const float* __restrict__ pm,
                                             const float* __restrict__ lnn,
                                             float* __restrict__ inter_part,
                                             int* __restrict__ ctr,
                                             float* __restrict__ out) {
    const int b    = blockIdx.x;
    const int t    = threadIdx.x;
    const int wave = t >> 6;
    const int lane = t & 63;

    __shared__ float red[4];
    __shared__ int   role;

    // Gram row b: waves stride over columns j > b
    {
        const float invS2 = 1.0f / ((float)S * (float)S);
        const float4 a = *(const float4*)(cs + (size_t)b * D + lane * 4);
        float my = 0.f;
        for (int j = b + 1 + wave; j < B; j += 4) {
            const float4 bb = *(const float4*)(cs + (size_t)j * D + lane * 4);
            float dot = a.x * bb.x + a.y * bb.y + a.z * bb.z + a.w * bb.w;
            #pragma unroll
            for (int m = 1; m < 64; m <<= 1) dot += __shfl_xor(dot, m, 64);
            my += fminf(dot * invS2, 1.0f);
        }
        if (lane == 0) red[wave] = my;
        __syncthreads();
        if (t == 0) inter_part[b] = red[0] + red[1] + red[2] + red[3];
        __syncthreads();
    }

    // last-block handoff (single atomic per block, no spin)
    if (t == 0) {
        __threadfence();  // release our inter_part store device-wide
        const int old = __hip_atomic_fetch_add(ctr, 1, __ATOMIC_ACQ_REL,
                                               __HIP_MEMORY_SCOPE_AGENT);
        role = (old == B - 1) ? 1 : 0;
    }
    __syncthreads();
    if (!role) return;

    // ---- finalize (winner block only; values independent of winner id) ----
    float my_inter = 0.f, my_intra = 0.f;
    if (t < B) {
        my_inter = inter_part[t];
        my_intra = fminf((sq[t] - (float)S) / ((float)S * (float)(S - 1)), 1.0f);
    }

    float my_hard = 0.f;
    for (int k = t; k < B * NNEG; k += 256) {
        const int bb = k >> 5, nk = k & 31;
        my_hard += fmaxf(lnn[nk] - pm[bb] + 1.0f, 0.f);
    }

    const float intra = block_sum256(my_intra, red, wave, lane) / (float)B;
    const float inter = block_sum256(my_inter, red, wave, lane) / (float)NPAIR;
    const float hard  = block_sum256(my_hard,  red, wave, lane) / (float)(B * NNEG);

    if (t == 0) {
        out[0] = intra;
        out[1] = inter;
        out[2] = hard;
        out[3] = intra + inter + 0.1f * hard;
    }
}

extern "C" void kernel_launch(void* const* d_in, const int* in_sizes, int n_in,
                              void* d_out, int out_size, void* d_ws, size_t ws_size,
                              hipStream_t stream) {
    const float* x   = (const float*)d_in[0];   // [B, S, D]
    const float* neg = (const float*)d_in[1];   // [NNEG, D]
    float* out = (float*)d_out;

    int*   ctr = (int*)d_ws;                    // zeroed by k1's extra block
    float* wf  = (float*)((char*)d_ws + 256);
    float* pblk       = wf;                          // G1*D = 524288
    float* praw       = pblk + (size_t)G1 * D;       // G1
    float* cs         = praw + G1;                   // B*D
    float* sq         = cs + (size_t)B * D;          // B
    float* pm         = sq + B;                      // B
    float* lnn        = pm + B;                      // NNEG
    float* inter_part = lnn + NNEG;                  // B

    k1<<<G1 + 1, 256, 0, stream>>>(x, neg, pblk, praw, lnn, ctr);
    k1b<<<B, 256, 0, stream>>>(pblk, praw, cs, sq, pm);
    k2fin<<<B, 256, 0, stream>>>(cs, sq, pm, lnn, inter_part, ctr, out);
}